// Round 1
// baseline (463.445 us; speedup 1.0000x reference)
//
#include <hip/hip_runtime.h>
#include <hip/hip_bf16.h>

typedef __bf16 bf16;
typedef bf16 bf16x8 __attribute__((ext_vector_type(8)));
typedef float f32x4 __attribute__((ext_vector_type(4)));

#define BSZ 8
#define NQ 900
#define NH 8
#define SUMHW 21504
#define NROW 7200

// NaN-guard bound: representable in bf16 (bf16 max ~3.39e38). fmaxf/fminf
// return the non-NaN operand, so NaN -> -BIGF. Real data is never near this,
// so the guard is mathematically neutral on the reference domain.
#define BIGF 3.3e38f

// ---------- runtime-dtype scalar load ----------
__device__ inline float ld_rt(const void* p, size_t i, int f32) {
  return f32 ? ((const float*)p)[i] : (float)((const bf16*)p)[i];
}

// ---------- runtime-dtype staging: 16 elems -> LDS bf16 ----------
__device__ inline void stage16_rt(const void* p, size_t i, bf16* dst, int f32) {
  if (f32) {
    const float* s = (const float*)p + i;
    bf16x8 lo, hi;
#pragma unroll
    for (int j = 0; j < 2; ++j) {
      float4 v0 = ((const float4*)s)[2 * j];
      float4 v1 = ((const float4*)s)[2 * j + 1];
      bf16x8& d = j ? hi : lo;
      d[0] = (bf16)v0.x; d[1] = (bf16)v0.y; d[2] = (bf16)v0.z; d[3] = (bf16)v0.w;
      d[4] = (bf16)v1.x; d[5] = (bf16)v1.y; d[6] = (bf16)v1.z; d[7] = (bf16)v1.w;
    }
    *(bf16x8*)dst = lo;
    *(bf16x8*)(dst + 8) = hi;
  } else {
    const bf16* s = (const bf16*)p + i;
    *(bf16x8*)dst = *(const bf16x8*)s;
    *(bf16x8*)(dst + 8) = *(const bf16x8*)(s + 8);
  }
}

// ---------------- dtype probe: flags[0]=is_f32, flags[1]=0, flags[2]=0 -------
// f32 data read as bf16 has ~46% of the interleaved mantissa-halves decoding to
// |x|>1000 (random exponent bits); genuine bf16 tensors have none. Threshold 32
// of 512 is >10 sigma from both sides -> deterministic across calls.
__global__ void probe_flags(const bf16* q, int* flags) {
  if (threadIdx.x != 0 || blockIdx.x != 0) return;
  int c = 0;
  for (int i = 0; i < 512; ++i) {
    float x = (float)q[i];
    if (!(fabsf(x) <= 1000.f)) c++;  // counts NaN too
  }
  flags[0] = (c > 32) ? 1 : 0;
  flags[1] = 0;
  flags[2] = 0;
}

// ------------- 256x256 transpose -> bf16 (Wt[n][k] = W[k][n]) -------------
__global__ __launch_bounds__(256) void transpose256(const void* __restrict__ in,
                                                    bf16* __restrict__ out,
                                                    const int* __restrict__ flags) {
  const int f32 = flags[0];
  int idx = blockIdx.x * 256 + threadIdx.x;
  int k = idx >> 8, n = idx & 255;
  out[n * 256 + k] = (bf16)ld_rt(in, idx, f32);
}

// ---- fused transpose of W_off(256x192)+W_attn(256x96) -> Wt_oa[288][256] ----
__global__ __launch_bounds__(256) void transpose_oa(const void* __restrict__ Woff,
                                                    const void* __restrict__ Wattn,
                                                    bf16* __restrict__ Wt,
                                                    const int* __restrict__ flags) {
  const int f32 = flags[0];
  int idx = blockIdx.x * 256 + threadIdx.x;  // 0..73727
  int n = idx >> 8, k = idx & 255;
  float v = (n < 192) ? ld_rt(Woff, (size_t)k * 192 + n, f32)
                      : ld_rt(Wattn, (size_t)k * 96 + (n - 192), f32);
  Wt[idx] = (bf16)v;
}

// -------------- C[rowbase..rowbase+M,256] = A @ Wt^T + bias --------------
// MFMA 16x16x32 bf16; A[m=lane&15][k=quad*8+j]; B[k][n=lane&15];
// C/D: col=lane&15, row=quad*4+reg (verified on-device, prior session R7).
template <typename TC>
__global__ __launch_bounds__(256) void gemm_nt_256(
    const void* __restrict__ A, const bf16* __restrict__ Wt,
    const void* __restrict__ bias, TC* __restrict__ C, int rowbase, int M,
    const int* __restrict__ aflags, const int* __restrict__ bflags) {
  __shared__ __align__(16) bf16 As[64][72];
  __shared__ __align__(16) bf16 Bs[256][72];
  const int af32 = aflags[0], bf32 = bflags[0];
  const int t = threadIdx.x;
  const int w = t >> 6, lane = t & 63;
  const int ml = lane & 15, qd = lane >> 4;
  const int blockM = blockIdx.x * 64;
  f32x4 acc[16] = {};

  for (int k0 = 0; k0 < 256; k0 += 64) {
    int r = t >> 2, c = (t & 3) * 16;
    int row = blockM + r;
    if (row > M - 1) row = M - 1;
    stage16_rt(A, ((size_t)rowbase + row) * 256 + k0 + c, &As[r][c], af32);
    const bf16* wsrc = Wt + t * 256 + k0;
#pragma unroll
    for (int j = 0; j < 8; ++j)
      *(bf16x8*)&Bs[t][j * 8] = *(const bf16x8*)(wsrc + j * 8);
    __syncthreads();
#pragma unroll
    for (int kc = 0; kc < 2; ++kc) {
      bf16x8 a = *(const bf16x8*)&As[w * 16 + ml][kc * 32 + qd * 8];
#pragma unroll
      for (int tn = 0; tn < 16; ++tn) {
        bf16x8 bb = *(const bf16x8*)&Bs[tn * 16 + ml][kc * 32 + qd * 8];
        acc[tn] = __builtin_amdgcn_mfma_f32_16x16x32_bf16(a, bb, acc[tn], 0, 0, 0);
      }
    }
    __syncthreads();
  }

#pragma unroll
  for (int tn = 0; tn < 16; ++tn) {
    int col = tn * 16 + ml;
    float bv = ld_rt(bias, col, bf32);
#pragma unroll
    for (int rr = 0; rr < 4; ++rr) {
      int row = blockM + w * 16 + qd * 4 + rr;
      float v = fminf(fmaxf(acc[tn][rr] + bv, -BIGF), BIGF);  // NaN-guard only
      if (row < M) C[((size_t)rowbase + row) * 256 + col] = (TC)v;
    }
  }
}

// ------ offsets+logits projection: [7200,256] @ Wt_oa[288,256]^T ------
__global__ __launch_bounds__(256) void gemm_oa(const void* __restrict__ query,
                                               const bf16* __restrict__ Wt,
                                               const void* __restrict__ boff,
                                               const void* __restrict__ battn,
                                               float* __restrict__ offs,
                                               float* __restrict__ logits,
                                               const int* __restrict__ flags) {
  __shared__ __align__(16) bf16 As[64][72];
  __shared__ __align__(16) bf16 Bs[288][72];
  const int f32 = flags[0];
  const int t = threadIdx.x;
  const int w = t >> 6, lane = t & 63;
  const int ml = lane & 15, qd = lane >> 4;
  const int blockM = blockIdx.x * 64;
  f32x4 acc[18] = {};

  for (int k0 = 0; k0 < 256; k0 += 64) {
    int r = t >> 2, c = (t & 3) * 16;
    int row = blockM + r;
    if (row > NROW - 1) row = NROW - 1;
    stage16_rt(query, (size_t)row * 256 + k0 + c, &As[r][c], f32);
    const bf16* wsrc = Wt + t * 256 + k0;
#pragma unroll
    for (int j = 0; j < 8; ++j)
      *(bf16x8*)&Bs[t][j * 8] = *(const bf16x8*)(wsrc + j * 8);
    if (t < 32) {
      const bf16* wsrc2 = Wt + (256 + t) * 256 + k0;
#pragma unroll
      for (int j = 0; j < 8; ++j)
        *(bf16x8*)&Bs[256 + t][j * 8] = *(const bf16x8*)(wsrc2 + j * 8);
    }
    __syncthreads();
#pragma unroll
    for (int kc = 0; kc < 2; ++kc) {
      bf16x8 a = *(const bf16x8*)&As[w * 16 + ml][kc * 32 + qd * 8];
#pragma unroll
      for (int tn = 0; tn < 18; ++tn) {
        bf16x8 bb = *(const bf16x8*)&Bs[tn * 16 + ml][kc * 32 + qd * 8];
        acc[tn] = __builtin_amdgcn_mfma_f32_16x16x32_bf16(a, bb, acc[tn], 0, 0, 0);
      }
    }
    __syncthreads();
  }

#pragma unroll
  for (int tn = 0; tn < 18; ++tn) {
    int col = tn * 16 + ml;
#pragma unroll
    for (int rr = 0; rr < 4; ++rr) {
      int row = blockM + w * 16 + qd * 4 + rr;
      if (row < NROW) {
        float v = acc[tn][rr];
        if (col < 192)
          offs[(size_t)row * 192 + col] = v + ld_rt(boff, col, f32);
        else
          logits[(size_t)row * 96 + (col - 192)] = v + ld_rt(battn, col - 192, f32);
      }
    }
  }
}

// ------ softmax + bilinear sampling + weighted accumulate ------
__global__ __launch_bounds__(256) void msda_sample(
    const bf16* __restrict__ value, const void* __restrict__ refp,
    const float* __restrict__ offs, const float* __restrict__ logits,
    bf16* __restrict__ accb, int b_base, size_t batch_stride,
    const int* __restrict__ flags) {
  const int f32 = flags[0];
  const int qi = blockIdx.x, bl = blockIdx.y;
  const int b = b_base + bl;
  const int row = b * NQ + qi;
  const int t = threadIdx.x, h = t >> 5, d = t & 31;
  const bf16* valb = value + (size_t)bl * batch_stride;

  const float* lg = logits + (size_t)(row * NH + h) * 12;
  float lv[12];
#pragma unroll
  for (int i = 0; i < 12; ++i) lv[i] = fminf(fmaxf(lg[i], -BIGF), BIGF);  // NaN-guard
  float mx = -BIGF;
#pragma unroll
  for (int i = 0; i < 12; ++i) mx = fmaxf(mx, lv[i]);
  float e[12], se = 0.f;
#pragma unroll
  for (int i = 0; i < 12; ++i) {
    e[i] = __expf(lv[i] - mx);  // lv-mx <= 0: no overflow possible
    se += e[i];
  }
  const float inv = 1.f / se;

  const float* of = offs + (size_t)(row * NH + h) * 24;
  const int Hs[3] = {128, 64, 32}, Wd[3] = {128, 64, 32}, st[3] = {0, 16384, 20480};
  float acc = 0.f;
#pragma unroll
  for (int l = 0; l < 3; ++l) {
    const int Hl = Hs[l], Wl = Wd[l];
    float rx = ld_rt(refp, (size_t)(row * 3 + l) * 2 + 0, f32);
    float ry = ld_rt(refp, (size_t)(row * 3 + l) * 2 + 1, f32);
    const bf16* base = valb + (size_t)st[l] * 256 + h * 32 + d;
#pragma unroll
    for (int p = 0; p < 4; ++p) {
      float ox = of[(l * 4 + p) * 2 + 0], oy = of[(l * 4 + p) * 2 + 1];
      float px = (rx + ox / (float)Wl) * (float)Wl - 0.5f;
      float py = (ry + oy / (float)Hl) * (float)Hl - 0.5f;
      // int-cast safety clamp. Any |px| > Wl makes all corners invalid
      // (contribution 0) both here and in the reference, so clamping at
      // 1e6 >> Wl is exactly neutral. NaN -> -1e6 -> invalid -> 0.
      px = fminf(fmaxf(px, -1e6f), 1e6f);
      py = fminf(fmaxf(py, -1e6f), 1e6f);
      const float x0f = floorf(px), y0f = floorf(py);
      const float lx = px - x0f, ly = py - y0f;
      const int x0 = (int)x0f, y0 = (int)y0f;
      const float wgt = e[l * 4 + p] * inv;
      float s = 0.f;
#pragma unroll
      for (int cy = 0; cy < 2; ++cy) {
        const int iy = y0 + cy;
        const float wy = cy ? ly : 1.f - ly;
        const bool vy = (iy >= 0) && (iy < Hl);
        const int iyc = iy < 0 ? 0 : (iy > Hl - 1 ? Hl - 1 : iy);
#pragma unroll
        for (int cx = 0; cx < 2; ++cx) {
          const int ix = x0 + cx;
          const float wx = cx ? lx : 1.f - lx;
          const bool vx = (ix >= 0) && (ix < Wl);
          const int ixc = ix < 0 ? 0 : (ix > Wl - 1 ? Wl - 1 : ix);
          float g = (float)base[(size_t)(iyc * Wl + ixc) * 256];
          g = fminf(fmaxf(g, -BIGF), BIGF);  // NaN-guard only
          s += (vx && vy) ? wx * wy * g : 0.f;
        }
      }
      acc += wgt * s;
    }
  }
  accb[(size_t)row * 256 + t] = (bf16)acc;
}

extern "C" void kernel_launch(void* const* d_in, const int* in_sizes, int n_in,
                              void* d_out, int out_size, void* d_ws, size_t ws_size,
                              hipStream_t stream) {
  // dict order (harness-guaranteed)
  const void* query = d_in[0];
  const void* refp = d_in[1];
  const void* inpf = d_in[2];
  const void* W_off = d_in[5];
  const void* b_off = d_in[6];
  const void* W_attn = d_in[7];
  const void* b_attn = d_in[8];
  const void* W_val = d_in[9];
  const void* b_val = d_in[10];
  const void* W_out = d_in[11];
  const void* b_out = d_in[12];

  float* out = (float*)d_out;  // reference output dtype = float32
  char* ws = (char*)d_ws;
  int* flags = (int*)ws;
  const int* bf16flag = flags + 2;         // always 0
  bf16* Wt_val = (bf16*)(ws + 256);        // 131072 B
  bf16* Wt_out = (bf16*)(ws + 131328);     // 131072 B
  bf16* Wt_oa = (bf16*)(ws + 262400);      // 147456 B
  float* offs = (float*)(ws + 409856);     // 5529600 B
  float* logits = (float*)(ws + 5939456);  // 2764800 B
  bf16* accb = (bf16*)(ws + 8704256);      // 3686400 B
  bf16* value = (bf16*)(ws + 12390656);    // chunk 11010048 | full 88080384
  const unsigned long long WS_FULL = 12390656ULL + 88080384ULL;
  const unsigned long long WS_TIGHT = 12390656ULL + 11010048ULL;

  const int pipeline_ok = ws_size >= WS_TIGHT;
  const int full = ws_size >= WS_FULL;

  probe_flags<<<1, 64, 0, stream>>>((const bf16*)query, flags);
  if (pipeline_ok) {
    transpose256<<<256, 256, 0, stream>>>(W_val, Wt_val, flags);
    transpose256<<<256, 256, 0, stream>>>(W_out, Wt_out, flags);
    transpose_oa<<<288, 256, 0, stream>>>(W_off, W_attn, Wt_oa, flags);
    gemm_oa<<<(NROW + 63) / 64, 256, 0, stream>>>(query, Wt_oa, b_off, b_attn, offs,
                                                  logits, flags);
    if (full) {
      gemm_nt_256<bf16><<<(BSZ * SUMHW) / 64, 256, 0, stream>>>(
          inpf, Wt_val, b_val, value, 0, BSZ * SUMHW, flags, flags);
      msda_sample<<<dim3(NQ, BSZ), 256, 0, stream>>>(
          value, refp, offs, logits, accb, 0, (size_t)SUMHW * 256, flags);
    } else {
      for (int b = 0; b < BSZ; ++b) {
        gemm_nt_256<bf16><<<SUMHW / 64, 256, 0, stream>>>(
            inpf, Wt_val, b_val, value - (size_t)b * SUMHW * 256, b * SUMHW, SUMHW,
            flags, flags);
        msda_sample<<<dim3(NQ, 1), 256, 0, stream>>>(value, refp, offs, logits, accb,
                                                     b, 0, flags);
      }
    }
    gemm_nt_256<float><<<(NROW + 63) / 64, 256, 0, stream>>>(
        accb, Wt_out, b_out, out, 0, NROW, bf16flag, flags);
  }
}